// Round 5
// baseline (711.012 us; speedup 1.0000x reference)
//
#include <hip/hip_runtime.h>

#define B_   4
#define S_   2048
#define D_   1024
#define DFF_ 4096

typedef __attribute__((ext_vector_type(8))) short short8;
typedef __attribute__((ext_vector_type(4))) float floatx4;

__device__ __forceinline__ unsigned short f2b(float f) {
    unsigned int u = __float_as_uint(f);
    unsigned int r = (u + 0x7fffu + ((u >> 16) & 1u)) >> 16;
    return (unsigned short)r;
}
__device__ __forceinline__ float b2f(unsigned short u) {
    return __uint_as_float((unsigned int)u << 16);
}

// XCD-aware swizzle: blocks sharing an A row-tile (same by) land on one XCD.
__device__ __forceinline__ void swizzle_xy(int gx, int gy, int& bx, int& by) {
    if ((gy & 7) == 0) {
        const int linear = by * gx + bx;
        const int xcd = linear & 7;
        const int slot = linear >> 3;
        const int r = slot / gx;
        by = xcd * (gy >> 3) + r;
        bx = slot - r * gx;
    }
}

// ---------------------------------------------------------------------------
// Shared GEMM core: 128x128 tile, BK=32, 4 waves (64x64 each).
// DOUBLE-BUFFERED single-barrier K-loop:
//   barrier -> issue loads(k+1)->buf^1 -> compute(k) from buf
// so the compiler's vmcnt(0)-before-barrier drains loads AFTER a compute
// phase (latency hidden) instead of immediately (m97's exposed drain).
// LDS swizzle: logical k-group g of row r stored at group g ^ ((r>>1)&3)
// -> b128 frag reads = 2 lanes/bank (free, m136).
// ---------------------------------------------------------------------------
__device__ __forceinline__ void gemm_core(
    const unsigned short* __restrict__ A,
    const unsigned short* __restrict__ Bt,
    int ldA, int ldB, int K, int m0, int n0,
    unsigned short* As, unsigned short* Bs,   // each 2*4096 elems (2 bufs)
    floatx4 acc[4][4])
{
    const int tid  = threadIdx.x;
    const int lane = tid & 63;
    const int wave = tid >> 6;

    const int ra = tid >> 2;                              // 0..63
    const int cg = ((tid & 3) ^ ((ra >> 1) & 3)) * 8;     // swizzled k-group
    const unsigned short* gA = A  + (long long)(m0 + ra) * ldA + cg;
    const unsigned short* gB = Bt + (long long)(n0 + ra) * ldB + cg;
    const long long pA2 = 64LL * ldA;
    const long long pB2 = 64LL * ldB;

    unsigned short* wA = As + wave * 512;
    unsigned short* wB = Bs + wave * 512;

    const int wr = (wave >> 1) * 64;
    const int wc = (wave & 1) * 64;
    const int fr = lane & 15;
    const int q  = lane >> 4;

    int aoff[4], boff[4];
#pragma unroll
    for (int i = 0; i < 4; i++) {
        const int rA = wr + i * 16 + fr;
        const int rB = wc + i * 16 + fr;
        aoff[i] = rA * 32 + ((q ^ ((rA >> 1) & 3)) * 8);
        boff[i] = rB * 32 + ((q ^ ((rB >> 1) & 3)) * 8);
    }

#define ISSUE(k0, bsel) do {                                                  \
    __builtin_amdgcn_global_load_lds(                                         \
        (const __attribute__((address_space(1))) void*)(gA + (k0)),           \
        (__attribute__((address_space(3))) void*)(wA + (bsel) * 4096), 16, 0, 0); \
    __builtin_amdgcn_global_load_lds(                                         \
        (const __attribute__((address_space(1))) void*)(gA + (k0) + pA2),     \
        (__attribute__((address_space(3))) void*)(wA + (bsel) * 4096 + 2048), 16, 0, 0); \
    __builtin_amdgcn_global_load_lds(                                         \
        (const __attribute__((address_space(1))) void*)(gB + (k0)),           \
        (__attribute__((address_space(3))) void*)(wB + (bsel) * 4096), 16, 0, 0); \
    __builtin_amdgcn_global_load_lds(                                         \
        (const __attribute__((address_space(1))) void*)(gB + (k0) + pB2),     \
        (__attribute__((address_space(3))) void*)(wB + (bsel) * 4096 + 2048), 16, 0, 0); \
} while (0)

    auto compute = [&](int bsel) {
        const unsigned short* cA = As + bsel * 4096;
        const unsigned short* cB = Bs + bsel * 4096;
        short8 af[4], bfr[4];
#pragma unroll
        for (int mi = 0; mi < 4; mi++) af[mi] = *(const short8*)&cA[aoff[mi]];
#pragma unroll
        for (int ni = 0; ni < 4; ni++) bfr[ni] = *(const short8*)&cB[boff[ni]];
#pragma unroll
        for (int mi = 0; mi < 4; mi++)
#pragma unroll
            for (int ni = 0; ni < 4; ni++)
                acc[mi][ni] = __builtin_amdgcn_mfma_f32_16x16x32_bf16(
                    af[mi], bfr[ni], acc[mi][ni], 0, 0, 0);
    };

    ISSUE(0, 0);
    int buf = 0;
    for (int k0 = 0; k0 < K - 32; k0 += 32) {
        __syncthreads();            // drains loads into buf (compiler vmcnt(0))
        ISSUE(k0 + 32, buf ^ 1);    // next tile in flight across compute
        compute(buf);
        buf ^= 1;
    }
    __syncthreads();
    compute(buf);
#undef ISSUE
}

// ---------------------------------------------------------------------------
__global__ __launch_bounds__(256) void cast_bf16_kernel(
    const float4* __restrict__ src, ushort4* __restrict__ dst, int n4)
{
    int i = blockIdx.x * 256 + threadIdx.x;
    if (i < n4) {
        float4 f = src[i];
        ushort4 u;
        u.x = f2b(f.x); u.y = f2b(f.y); u.z = f2b(f.z); u.w = f2b(f.w);
        dst[i] = u;
    }
}

// ---------------------------------------------------------------------------
__global__ __launch_bounds__(256) void transpose_cast_kernel(
    const float* __restrict__ W, unsigned short* __restrict__ Wt, int K, int N)
{
    __shared__ float tile[32][33];
    const int tx = threadIdx.x;
    const int ty = threadIdx.y;
    const int bx = blockIdx.x * 32;
    const int by = blockIdx.y * 32;
#pragma unroll
    for (int j = 0; j < 32; j += 8)
        tile[ty + j][tx] = W[(long long)(by + ty + j) * N + bx + tx];
    __syncthreads();
#pragma unroll
    for (int j = 0; j < 32; j += 8)
        Wt[(long long)(bx + ty + j) * K + by + tx] = f2b(tile[tx][ty + j]);
}

// ---------------------------------------------------------------------------
// GEMM: C = act(scale * A @ Bt^T + bias), batched via z
// ---------------------------------------------------------------------------
template <int OUT_BF16, int ACT_LEAKY, int HAS_BIAS>
__global__ __launch_bounds__(256) void gemm_bt(
    const unsigned short* __restrict__ A,
    const unsigned short* __restrict__ Bt,
    void* __restrict__ Cptr,
    const float* __restrict__ bias,
    int M, int N, int K, float scale,
    long long sA, long long sB, long long sC)
{
    __shared__ unsigned short As[2 * 4096];
    __shared__ unsigned short Bs[2 * 4096];

    const int lane = threadIdx.x & 63;
    const int wave = threadIdx.x >> 6;
    const int z    = blockIdx.z;

    int bx = blockIdx.x, by = blockIdx.y;
    swizzle_xy(gridDim.x, gridDim.y, bx, by);
    const int m0 = by * 128;
    const int n0 = bx * 128;

    floatx4 acc[4][4];
#pragma unroll
    for (int i = 0; i < 4; i++)
#pragma unroll
        for (int j = 0; j < 4; j++) acc[i][j] = floatx4{0.f, 0.f, 0.f, 0.f};

    gemm_core(A + (long long)z * sA, Bt + (long long)z * sB,
              K, K, K, m0, n0, As, Bs, acc);

    const int wr = (wave >> 1) * 64;
    const int wc = (wave & 1) * 64;
    const int cr = (lane >> 4) * 4;
    const int cc = lane & 15;
    float* Cf = (float*)Cptr;
    unsigned short* Cb = (unsigned short*)Cptr;

#pragma unroll
    for (int mi = 0; mi < 4; mi++) {
#pragma unroll
        for (int ni = 0; ni < 4; ni++) {
            const int col = n0 + wc + ni * 16 + cc;
            const float bv = HAS_BIAS ? bias[col] : 0.0f;
#pragma unroll
            for (int r = 0; r < 4; r++) {
                const int row = m0 + wr + mi * 16 + cr + r;
                float v = acc[mi][ni][r] * scale + bv;
                if (ACT_LEAKY) v = (v > 0.0f) ? v : 0.01f * v;
                const long long idx = (long long)z * sC + (long long)row * N + col;
                if (OUT_BF16) Cb[idx] = f2b(v); else Cf[idx] = v;
            }
        }
    }
}

// ---------------------------------------------------------------------------
// Split-K GEMM: blockIdx.z = b * NK + ks; partial P[(ks*nb + b)][M][N]
// PBF16: partials stored bf16 (for AV), else fp32.
// ---------------------------------------------------------------------------
template <int NK, int PBF16>
__global__ __launch_bounds__(256) void gemm_bt_sk(
    const unsigned short* __restrict__ A,
    const unsigned short* __restrict__ Bt,
    void* __restrict__ Pptr,
    int M, int N, int Kslice, int ldA, int ldB,
    long long sA, long long sB)
{
    __shared__ unsigned short As[2 * 4096];
    __shared__ unsigned short Bs[2 * 4096];

    const int lane = threadIdx.x & 63;
    const int wave = threadIdx.x >> 6;
    const int z    = blockIdx.z;
    const int ks   = z % NK;
    const int b    = z / NK;
    const int nb   = gridDim.z / NK;

    int bx = blockIdx.x, by = blockIdx.y;
    swizzle_xy(gridDim.x, gridDim.y, bx, by);
    const int m0 = by * 128;
    const int n0 = bx * 128;

    floatx4 acc[4][4];
#pragma unroll
    for (int i = 0; i < 4; i++)
#pragma unroll
        for (int j = 0; j < 4; j++) acc[i][j] = floatx4{0.f, 0.f, 0.f, 0.f};

    gemm_core(A + (long long)b * sA + (long long)ks * Kslice,
              Bt + (long long)b * sB + (long long)ks * Kslice,
              ldA, ldB, Kslice, m0, n0, As, Bs, acc);

    const long long pbase = ((long long)ks * nb + b) * (long long)M * N;

    const int wr = (wave >> 1) * 64;
    const int wc = (wave & 1) * 64;
    const int cr = (lane >> 4) * 4;
    const int cc = lane & 15;
    float* Pf = (float*)Pptr;
    unsigned short* Ph = (unsigned short*)Pptr;

#pragma unroll
    for (int mi = 0; mi < 4; mi++) {
#pragma unroll
        for (int ni = 0; ni < 4; ni++) {
            const int col = n0 + wc + ni * 16 + cc;
#pragma unroll
            for (int r = 0; r < 4; r++) {
                const int row = m0 + wr + mi * 16 + cr + r;
                const long long idx = pbase + (long long)row * N + col;
                if (PBF16) Ph[idx] = f2b(acc[mi][ni][r]);
                else       Pf[idx] = acc[mi][ni][r];
            }
        }
    }
}

// ---------------------------------------------------------------------------
// Fused QKV GEMM: A[8192,1024] @ Wqkvt[3072,1024]^T
// seg 0 -> Qb bf16, seg 1 -> Kb bf16, seg 2 -> Vt[b][c][s] bf16
// ---------------------------------------------------------------------------
__global__ __launch_bounds__(256) void gemm_qkv(
    const unsigned short* __restrict__ A,
    const unsigned short* __restrict__ Bt,
    unsigned short* __restrict__ Qb,
    unsigned short* __restrict__ Kb,
    unsigned short* __restrict__ Vt,
    const float* __restrict__ bq,
    const float* __restrict__ bk,
    const float* __restrict__ bv)
{
    __shared__ unsigned short As[2 * 4096];
    __shared__ unsigned short Bs[2 * 4096];

    const int lane = threadIdx.x & 63;
    const int wave = threadIdx.x >> 6;

    int bx = blockIdx.x, by = blockIdx.y;
    swizzle_xy(gridDim.x, gridDim.y, bx, by);
    const int m0 = by * 128;
    const int n0 = bx * 128;

    floatx4 acc[4][4];
#pragma unroll
    for (int i = 0; i < 4; i++)
#pragma unroll
        for (int j = 0; j < 4; j++) acc[i][j] = floatx4{0.f, 0.f, 0.f, 0.f};

    gemm_core(A, Bt, D_, D_, D_, m0, n0, As, Bs, acc);

    const int wr = (wave >> 1) * 64;
    const int wc = (wave & 1) * 64;
    const int cr = (lane >> 4) * 4;
    const int cc = lane & 15;

#pragma unroll
    for (int mi = 0; mi < 4; mi++) {
#pragma unroll
        for (int ni = 0; ni < 4; ni++) {
            const int col = n0 + wc + ni * 16 + cc;
            const int seg = col >> 10;
            const int c = col & 1023;
            const float* bp = (seg == 0) ? bq : ((seg == 1) ? bk : bv);
            const float bval = bp[c];
#pragma unroll
            for (int r = 0; r < 4; r++) {
                const int row = m0 + wr + mi * 16 + cr + r;
                const unsigned short o = f2b(acc[mi][ni][r] + bval);
                if (seg == 0) {
                    Qb[(long long)row * D_ + c] = o;
                } else if (seg == 1) {
                    Kb[(long long)row * D_ + c] = o;
                } else {
                    const int b = row >> 11;
                    const int s = row & (S_ - 1);
                    Vt[((long long)b * D_ + c) * S_ + s] = o;
                }
            }
        }
    }
}

// ---------------------------------------------------------------------------
// AV reduce: bf16 out = p0 + p1 (bf16 partials)
// ---------------------------------------------------------------------------
__global__ __launch_bounds__(256) void avred_kernel(
    const ushort4* __restrict__ p0, const ushort4* __restrict__ p1,
    ushort4* __restrict__ dst, int n4)
{
    int i = blockIdx.x * 256 + threadIdx.x;
    if (i < n4) {
        ushort4 a = p0[i], b = p1[i];
        ushort4 u;
        u.x = f2b(b2f(a.x) + b2f(b.x)); u.y = f2b(b2f(a.y) + b2f(b.y));
        u.z = f2b(b2f(a.z) + b2f(b.z)); u.w = f2b(b2f(a.w) + b2f(b.w));
        dst[i] = u;
    }
}

// ---------------------------------------------------------------------------
// Fused split-K reduce + bias + residual + LayerNorm (fp32 partials).
// ---------------------------------------------------------------------------
template <int HAS_OUTB>
__global__ __launch_bounds__(256) void ln_red_kernel(
    const float* __restrict__ p0, const float* __restrict__ p1,
    const float* __restrict__ resid, const float* __restrict__ bias,
    const float* __restrict__ g, const float* __restrict__ b,
    float* __restrict__ out_f, unsigned short* __restrict__ out_b)
{
    __shared__ float red[8];
    const long long row = blockIdx.x;
    const int tid = threadIdx.x;
    const float4 a0 = ((const float4*)(p0 + row * D_))[tid];
    const float4 a1 = ((const float4*)(p1 + row * D_))[tid];
    const float4 rv = ((const float4*)(resid + row * D_))[tid];
    const float4 bi = ((const float4*)bias)[tid];
    float v0 = a0.x + a1.x + bi.x + rv.x;
    float v1 = a0.y + a1.y + bi.y + rv.y;
    float v2 = a0.z + a1.z + bi.z + rv.z;
    float v3 = a0.w + a1.w + bi.w + rv.w;

    float s = v0 + v1 + v2 + v3;
#pragma unroll
    for (int o = 32; o > 0; o >>= 1) s += __shfl_xor(s, o);
    if ((tid & 63) == 0) red[tid >> 6] = s;
    __syncthreads();
    const float mean = (red[0] + red[1] + red[2] + red[3]) * (1.0f / D_);

    const float d0 = v0 - mean, d1 = v1 - mean, d2 = v2 - mean, d3 = v3 - mean;
    float q = d0 * d0 + d1 * d1 + d2 * d2 + d3 * d3;
#pragma unroll
    for (int o = 32; o > 0; o >>= 1) q += __shfl_xor(q, o);
    if ((tid & 63) == 0) red[4 + (tid >> 6)] = q;
    __syncthreads();
    const float var = (red[4] + red[5] + red[6] + red[7]) * (1.0f / D_);
    const float inv = rsqrtf(var + 1e-6f);

    const float4 gv = ((const float4*)g)[tid];
    const float4 bv = ((const float4*)b)[tid];
    const float o0 = d0 * inv * gv.x + bv.x;
    const float o1 = d1 * inv * gv.y + bv.y;
    const float o2 = d2 * inv * gv.z + bv.z;
    const float o3 = d3 * inv * gv.w + bv.w;

    ((float4*)(out_f + row * D_))[tid] = float4{o0, o1, o2, o3};
    if (HAS_OUTB) {
        ushort4 u; u.x = f2b(o0); u.y = f2b(o1); u.z = f2b(o2); u.w = f2b(o3);
        ((ushort4*)(out_b + row * D_))[tid] = u;
    }
}

// ---------------------------------------------------------------------------
// softmax over rows of bf16 scores [B*S, S] + fp32 intensity -> bf16 attn
// ---------------------------------------------------------------------------
__global__ __launch_bounds__(256) void softmax_bias_kernel(
    const unsigned short* __restrict__ scores, const float* __restrict__ intensity,
    unsigned short* __restrict__ attn)
{
    __shared__ float red[8];
    const long long row = blockIdx.x;
    const int tid = threadIdx.x;
    const ushort4* s4 = (const ushort4*)(scores + row * S_);
    const float4* i4 = (const float4*)(intensity + row * S_);
    ushort4* dst = (ushort4*)(attn + row * S_);

    float vv[8];
    {
        ushort4 a = s4[tid], b = s4[tid + 256];
        vv[0] = b2f(a.x); vv[1] = b2f(a.y); vv[2] = b2f(a.z); vv[3] = b2f(a.w);
        vv[4] = b2f(b.x); vv[5] = b2f(b.y); vv[6] = b2f(b.z); vv[7] = b2f(b.w);
    }

    float mx = vv[0];
#pragma unroll
    for (int i = 1; i < 8; i++) mx = fmaxf(mx, vv[i]);
#pragma unroll
    for (int o = 32; o > 0; o >>= 1) mx = fmaxf(mx, __shfl_xor(mx, o));
    if ((tid & 63) == 0) red[tid >> 6] = mx;
    __syncthreads();
    mx = fmaxf(fmaxf(red[0], red[1]), fmaxf(red[2], red[3]));

    float e[8];
    float sum = 0.f;
#pragma unroll
    for (int i = 0; i < 8; i++) { e[i] = __expf(vv[i] - mx); sum += e[i]; }
#pragma unroll
    for (int o = 32; o > 0; o >>= 1) sum += __shfl_xor(sum, o);
    if ((tid & 63) == 0) red[4 + (tid >> 6)] = sum;
    __syncthreads();
    sum = red[4] + red[5] + red[6] + red[7];
    const float rs = 1.0f / sum;

#pragma unroll
    for (int i = 0; i < 2; i++) {
        float4 iv = i4[tid + 256 * i];
        ushort4 o;
        o.x = f2b(e[4 * i + 0] * rs + iv.x);
        o.y = f2b(e[4 * i + 1] * rs + iv.y);
        o.z = f2b(e[4 * i + 2] * rs + iv.z);
        o.w = f2b(e[4 * i + 3] * rs + iv.w);
        dst[tid + 256 * i] = o;
    }
}

// ---------------------------------------------------------------------------
extern "C" void kernel_launch(void* const* d_in, const int* in_sizes, int n_in,
                              void* d_out, int out_size, void* d_ws, size_t ws_size,
                              hipStream_t stream)
{
    const float* X   = (const float*)d_in[0];
    const float* inten = (const float*)d_in[1];
    const float* Wq  = (const float*)d_in[2];
    const float* bq  = (const float*)d_in[3];
    const float* Wk  = (const float*)d_in[4];
    const float* bk  = (const float*)d_in[5];
    const float* Wv  = (const float*)d_in[6];
    const float* bv  = (const float*)d_in[7];
    const float* Wo  = (const float*)d_in[8];
    const float* bo  = (const float*)d_in[9];
    const float* W1  = (const float*)d_in[10];
    const float* b1  = (const float*)d_in[11];
    const float* W2  = (const float*)d_in[12];
    const float* b2  = (const float*)d_in[13];
    const float* g1  = (const float*)d_in[14];
    const float* be1 = (const float*)d_in[15];
    const float* g2  = (const float*)d_in[16];
    const float* be2 = (const float*)d_in[17];
    float* out = (float*)d_out;

    char* ws = (char*)d_ws;
    const size_t MB = 1ull << 20;
    unsigned short* Xb   = (unsigned short*)(ws + 0);        // 16MB; dead after QKV
    unsigned short* Wqkv = (unsigned short*)(ws + 16 * MB);  // 6MB
    unsigned short* Wot  = (unsigned short*)(ws + 22 * MB);  // 2MB
    unsigned short* W1t  = (unsigned short*)(ws + 24 * MB);  // 8MB
    unsigned short* W2t  = (unsigned short*)(ws + 32 * MB);  // 8MB
    unsigned short* Qb   = (unsigned short*)(ws + 40 * MB);  // 16MB; dead after scores
    unsigned short* Kb   = (unsigned short*)(ws + 56 * MB);  // 16MB; dead after scores
    unsigned short* Vt   = (unsigned short*)(ws + 72 * MB);  // 16MB; dead after attnV
    unsigned short* Sc   = (unsigned short*)(ws + 88 * MB);  // 32MB bf16; dead after softmax
    unsigned short* At   = (unsigned short*)(ws + 152 * MB); // 32MB; dead after attnV
    unsigned short* AVp  = (unsigned short*)(ws + 88 * MB);  // 32MB bf16 (2 parts; reuse Sc)
    unsigned short* AVb  = (unsigned short*)(ws + 0);        // 16MB (reuse Xb)
    float*          Op   = (float*)(ws + 152 * MB);          // 64MB fp32 (2 parts; reuse At)
    float*          Hf   = (float*)(ws + 40 * MB);           // 32MB (reuse Qb+Kb)
    unsigned short* Hb   = (unsigned short*)(ws + 72 * MB);  // 16MB (reuse Vt)
    unsigned short* F1   = (unsigned short*)(ws + 88 * MB);  // 64MB (reuse AVp+)
    float*          Fp   = (float*)(ws + 152 * MB);          // 64MB fp32 (2 parts; reuse Op)

    const dim3 blk(256);
    const dim3 tblk(32, 8);
    const long long MN_d = (long long)B_ * S_ * D_;

    // casts / weight transposes
    cast_bf16_kernel<<<dim3(8192), blk, 0, stream>>>(
        (const float4*)X, (ushort4*)Xb, B_ * S_ * D_ / 4);
    transpose_cast_kernel<<<dim3(D_ / 32, D_ / 32), tblk, 0, stream>>>(
        Wq, Wqkv, D_, D_);
    transpose_cast_kernel<<<dim3(D_ / 32, D_ / 32), tblk, 0, stream>>>(
        Wk, Wqkv + 1024 * 1024, D_, D_);
    transpose_cast_kernel<<<dim3(D_ / 32, D_ / 32), tblk, 0, stream>>>(
        Wv, Wqkv + 2048 * 1024, D_, D_);
    transpose_cast_kernel<<<dim3(D_ / 32, D_ / 32), tblk, 0, stream>>>(Wo, Wot, D_, D_);
    transpose_cast_kernel<<<dim3(DFF_ / 32, D_ / 32), tblk, 0, stream>>>(W1, W1t, D_, DFF_);
    transpose_cast_kernel<<<dim3(D_ / 32, DFF_ / 32), tblk, 0, stream>>>(W2, W2t, DFF_, D_);

    // fused QKV: 1536 blocks
    gemm_qkv<<<dim3(24, 64), blk, 0, stream>>>(Xb, Wqkv, Qb, Kb, Vt, bq, bk, bv);

    // scores = Q @ K^T / 32 -> bf16, 1024 blocks
    gemm_bt<1, 0, 0><<<dim3(16, 16, 4), blk, 0, stream>>>(
        Qb, Kb, Sc, nullptr, S_, S_, D_, 0.03125f,
        (long long)S_ * D_, (long long)S_ * D_, (long long)S_ * S_);

    // attn = softmax(scores) + intensity  (bf16)
    softmax_bias_kernel<<<dim3(B_ * S_), blk, 0, stream>>>(Sc, inten, At);

    // AV split-K=2: bf16 partials, 1024 blocks
    gemm_bt_sk<2, 1><<<dim3(8, 16, 8), blk, 0, stream>>>(
        At, Vt, AVp, S_, D_, S_ / 2, S_, S_,
        (long long)S_ * S_, (long long)D_ * S_);
    avred_kernel<<<dim3(8192), blk, 0, stream>>>(
        (const ushort4*)AVp, (const ushort4*)(AVp + MN_d), (ushort4*)AVb,
        (int)(MN_d / 4));

    // O-proj split-K=2: fp32 partials, 1024 blocks
    gemm_bt_sk<2, 0><<<dim3(8, 64, 2), blk, 0, stream>>>(
        AVb, Wot, Op, B_ * S_, D_, D_ / 2, D_, D_, 0, 0);

    // h = LN(Op0 + Op1 + bo + X) -> Hf fp32 + Hb bf16
    ln_red_kernel<1><<<dim3(B_ * S_), blk, 0, stream>>>(
        Op, Op + MN_d, X, bo, g1, be1, Hf, Hb);

    // F1 = leaky_relu(h @ W1 + b1)  (bf16), 2048 blocks
    gemm_bt<1, 1, 1><<<dim3(32, 64), blk, 0, stream>>>(
        Hb, W1t, F1, b1, B_ * S_, DFF_, D_, 1.0f, 0, 0, 0);

    // ffn2 split-K=2: fp32 partials, 1024 blocks
    gemm_bt_sk<2, 0><<<dim3(8, 64, 2), blk, 0, stream>>>(
        F1, W2t, Fp, B_ * S_, D_, DFF_ / 2, DFF_, DFF_, 0, 0);

    // out = LN(Fp0 + Fp1 + b2 + h)
    ln_red_kernel<0><<<dim3(B_ * S_), blk, 0, stream>>>(
        Fp, Fp + MN_d, Hf, b2, g2, be2, out, nullptr);
}

// Round 6
// 576.253 us; speedup vs baseline: 1.2339x; 1.2339x over previous
//
#include <hip/hip_runtime.h>

#define B_   4
#define S_   2048
#define D_   1024
#define DFF_ 4096

typedef __attribute__((ext_vector_type(8))) short short8;
typedef __attribute__((ext_vector_type(4))) float floatx4;

__device__ __forceinline__ unsigned short f2b(float f) {
    unsigned int u = __float_as_uint(f);
    unsigned int r = (u + 0x7fffu + ((u >> 16) & 1u)) >> 16;
    return (unsigned short)r;
}
__device__ __forceinline__ float b2f(unsigned short u) {
    return __uint_as_float((unsigned int)u << 16);
}

// XCD-aware swizzle: blocks sharing an A row-tile (same by) land on one XCD.
__device__ __forceinline__ void swizzle_xy(int gx, int gy, int& bx, int& by) {
    if ((gy & 7) == 0) {
        const int linear = by * gx + bx;
        const int xcd = linear & 7;
        const int slot = linear >> 3;
        const int r = slot / gx;
        by = xcd * (gy >> 3) + r;
        bx = slot - r * gx;
    }
}

// ---------------------------------------------------------------------------
// GEMM core: 256x128 tile, BK=64, 512 threads / 8 waves (each 64x64).
// 2-barrier K-loop (proven structure). LDS: As[256][64] 32KB + Bs[128][64]
// 16KB = 48KB. XOR swizzle: logical k-group g of row r stored at g ^ (r&7)
// -> b128 frag reads 2 lanes/bank (free); staging stays global_load_lds-
// compatible (lane's dest = wave base + lane*16B).
// Rationale: 256-row tile stages 0.0114 B/FLOP vs 128-tile's 0.0156 ->
// burst L2 demand ~39 B/cyc/CU vs 53 (L2 ceiling ~56). Halves B re-fetch.
// ---------------------------------------------------------------------------
__device__ __forceinline__ void gemm_core256(
    const unsigned short* __restrict__ A,
    const unsigned short* __restrict__ Bt,
    int ldA, int ldB, int K, int m0, int n0,
    unsigned short* As, unsigned short* Bs,
    floatx4 acc[4][4])
{
    const int tid  = threadIdx.x;   // 0..511
    const int lane = tid & 63;
    const int wave = tid >> 6;      // 0..7

    const int ra = tid >> 3;        // 0..63 (row within pass)
    const int pg = tid & 7;         // physical k-group
    const int cg = (pg ^ (ra & 7)) * 8;   // logical k-group loaded
    const unsigned short* gA = A  + (long long)(m0 + ra) * ldA + cg;
    const unsigned short* gB = Bt + (long long)(n0 + ra) * ldB + cg;
    const long long pA = 64LL * ldA;
    const long long pB = 64LL * ldB;

    unsigned short* dA = As + wave * 512;   // + pass*4096, + lane*8 (HW)
    unsigned short* dB = Bs + wave * 512;

    const int wr = (wave >> 1) * 64;  // 0..192
    const int wc = (wave & 1) * 64;   // 0 or 64
    const int fr = lane & 15;
    const int q  = lane >> 4;

    int aoff[2][4], boff[2][4];
#pragma unroll
    for (int h = 0; h < 2; h++)
#pragma unroll
        for (int i = 0; i < 4; i++) {
            const int rA = wr + i * 16 + fr;
            const int rB = wc + i * 16 + fr;
            const int g  = h * 4 + q;
            aoff[h][i] = rA * 64 + ((g ^ (rA & 7)) * 8);
            boff[h][i] = rB * 64 + ((g ^ (rB & 7)) * 8);
        }

    for (int k0 = 0; k0 < K; k0 += 64) {
        __syncthreads();
#pragma unroll
        for (int p = 0; p < 4; p++)
            __builtin_amdgcn_global_load_lds(
                (const __attribute__((address_space(1))) void*)(gA + k0 + p * pA),
                (__attribute__((address_space(3))) void*)(dA + p * 4096), 16, 0, 0);
#pragma unroll
        for (int p = 0; p < 2; p++)
            __builtin_amdgcn_global_load_lds(
                (const __attribute__((address_space(1))) void*)(gB + k0 + p * pB),
                (__attribute__((address_space(3))) void*)(dB + p * 4096), 16, 0, 0);
        __syncthreads();

#pragma unroll
        for (int h = 0; h < 2; h++) {
            short8 af[4], bfr[4];
#pragma unroll
            for (int mi = 0; mi < 4; mi++) af[mi] = *(const short8*)&As[aoff[h][mi]];
#pragma unroll
            for (int ni = 0; ni < 4; ni++) bfr[ni] = *(const short8*)&Bs[boff[h][ni]];
#pragma unroll
            for (int mi = 0; mi < 4; mi++)
#pragma unroll
                for (int ni = 0; ni < 4; ni++)
                    acc[mi][ni] = __builtin_amdgcn_mfma_f32_16x16x32_bf16(
                        af[mi], bfr[ni], acc[mi][ni], 0, 0, 0);
        }
    }
}

// ---------------------------------------------------------------------------
__global__ __launch_bounds__(256) void cast_bf16_kernel(
    const float4* __restrict__ src, ushort4* __restrict__ dst, int n4)
{
    int i = blockIdx.x * 256 + threadIdx.x;
    if (i < n4) {
        float4 f = src[i];
        ushort4 u;
        u.x = f2b(f.x); u.y = f2b(f.y); u.z = f2b(f.z); u.w = f2b(f.w);
        dst[i] = u;
    }
}

// ---------------------------------------------------------------------------
__global__ __launch_bounds__(256) void transpose_cast_kernel(
    const float* __restrict__ W, unsigned short* __restrict__ Wt, int K, int N)
{
    __shared__ float tile[32][33];
    const int tx = threadIdx.x;
    const int ty = threadIdx.y;
    const int bx = blockIdx.x * 32;
    const int by = blockIdx.y * 32;
#pragma unroll
    for (int j = 0; j < 32; j += 8)
        tile[ty + j][tx] = W[(long long)(by + ty + j) * N + bx + tx];
    __syncthreads();
#pragma unroll
    for (int j = 0; j < 32; j += 8)
        Wt[(long long)(bx + ty + j) * K + by + tx] = f2b(tile[tx][ty + j]);
}

// ---------------------------------------------------------------------------
// GEMM: C = act(scale * A @ Bt^T + bias), batched via z. 256x128 tile.
// ---------------------------------------------------------------------------
template <int OUT_BF16, int ACT_LEAKY, int HAS_BIAS>
__global__ __launch_bounds__(512, 4) void gemm_bt(
    const unsigned short* __restrict__ A,
    const unsigned short* __restrict__ Bt,
    void* __restrict__ Cptr,
    const float* __restrict__ bias,
    int M, int N, int K, float scale,
    long long sA, long long sB, long long sC)
{
    __shared__ unsigned short As[256 * 64];
    __shared__ unsigned short Bs[128 * 64];

    const int lane = threadIdx.x & 63;
    const int wave = threadIdx.x >> 6;
    const int z    = blockIdx.z;

    int bx = blockIdx.x, by = blockIdx.y;
    swizzle_xy(gridDim.x, gridDim.y, bx, by);
    const int m0 = by * 256;
    const int n0 = bx * 128;

    floatx4 acc[4][4];
#pragma unroll
    for (int i = 0; i < 4; i++)
#pragma unroll
        for (int j = 0; j < 4; j++) acc[i][j] = floatx4{0.f, 0.f, 0.f, 0.f};

    gemm_core256(A + (long long)z * sA, Bt + (long long)z * sB,
                 K, K, K, m0, n0, As, Bs, acc);

    const int wr = (wave >> 1) * 64;
    const int wc = (wave & 1) * 64;
    const int cr = (lane >> 4) * 4;
    const int cc = lane & 15;
    float* Cf = (float*)Cptr;
    unsigned short* Cb = (unsigned short*)Cptr;

#pragma unroll
    for (int mi = 0; mi < 4; mi++) {
#pragma unroll
        for (int ni = 0; ni < 4; ni++) {
            const int col = n0 + wc + ni * 16 + cc;
            const float bv = HAS_BIAS ? bias[col] : 0.0f;
#pragma unroll
            for (int r = 0; r < 4; r++) {
                const int row = m0 + wr + mi * 16 + cr + r;
                float v = acc[mi][ni][r] * scale + bv;
                if (ACT_LEAKY) v = (v > 0.0f) ? v : 0.01f * v;
                const long long idx = (long long)z * sC + (long long)row * N + col;
                if (OUT_BF16) Cb[idx] = f2b(v); else Cf[idx] = v;
            }
        }
    }
}

// ---------------------------------------------------------------------------
// Split-K GEMM, 256x128 tile: blockIdx.z = b * NK + ks;
// partial P[(ks*nb + b)][M][N]; PBF16 selects bf16 partial storage.
// ---------------------------------------------------------------------------
template <int NK, int PBF16>
__global__ __launch_bounds__(512, 4) void gemm_bt_sk(
    const unsigned short* __restrict__ A,
    const unsigned short* __restrict__ Bt,
    void* __restrict__ Pptr,
    int M, int N, int Kslice, int ldA, int ldB,
    long long sA, long long sB)
{
    __shared__ unsigned short As[256 * 64];
    __shared__ unsigned short Bs[128 * 64];

    const int lane = threadIdx.x & 63;
    const int wave = threadIdx.x >> 6;
    const int z    = blockIdx.z;
    const int ks   = z % NK;
    const int b    = z / NK;
    const int nb   = gridDim.z / NK;

    int bx = blockIdx.x, by = blockIdx.y;
    swizzle_xy(gridDim.x, gridDim.y, bx, by);
    const int m0 = by * 256;
    const int n0 = bx * 128;

    floatx4 acc[4][4];
#pragma unroll
    for (int i = 0; i < 4; i++)
#pragma unroll
        for (int j = 0; j < 4; j++) acc[i][j] = floatx4{0.f, 0.f, 0.f, 0.f};

    gemm_core256(A + (long long)b * sA + (long long)ks * Kslice,
                 Bt + (long long)b * sB + (long long)ks * Kslice,
                 ldA, ldB, Kslice, m0, n0, As, Bs, acc);

    const long long pbase = ((long long)ks * nb + b) * (long long)M * N;

    const int wr = (wave >> 1) * 64;
    const int wc = (wave & 1) * 64;
    const int cr = (lane >> 4) * 4;
    const int cc = lane & 15;
    float* Pf = (float*)Pptr;
    unsigned short* Ph = (unsigned short*)Pptr;

#pragma unroll
    for (int mi = 0; mi < 4; mi++) {
#pragma unroll
        for (int ni = 0; ni < 4; ni++) {
            const int col = n0 + wc + ni * 16 + cc;
#pragma unroll
            for (int r = 0; r < 4; r++) {
                const int row = m0 + wr + mi * 16 + cr + r;
                const long long idx = pbase + (long long)row * N + col;
                if (PBF16) Ph[idx] = f2b(acc[mi][ni][r]);
                else       Pf[idx] = acc[mi][ni][r];
            }
        }
    }
}

// ---------------------------------------------------------------------------
// Fused QKV GEMM, 256x128 tile: A[8192,1024] @ Wqkvt[3072,1024]^T
// seg 0 -> Qb bf16, seg 1 -> Kb bf16, seg 2 -> Vt[b][c][s] bf16
// ---------------------------------------------------------------------------
__global__ __launch_bounds__(512, 4) void gemm_qkv(
    const unsigned short* __restrict__ A,
    const unsigned short* __restrict__ Bt,
    unsigned short* __restrict__ Qb,
    unsigned short* __restrict__ Kb,
    unsigned short* __restrict__ Vt,
    const float* __restrict__ bq,
    const float* __restrict__ bk,
    const float* __restrict__ bv)
{
    __shared__ unsigned short As[256 * 64];
    __shared__ unsigned short Bs[128 * 64];

    const int lane = threadIdx.x & 63;
    const int wave = threadIdx.x >> 6;

    int bx = blockIdx.x, by = blockIdx.y;
    swizzle_xy(gridDim.x, gridDim.y, bx, by);
    const int m0 = by * 256;
    const int n0 = bx * 128;

    floatx4 acc[4][4];
#pragma unroll
    for (int i = 0; i < 4; i++)
#pragma unroll
        for (int j = 0; j < 4; j++) acc[i][j] = floatx4{0.f, 0.f, 0.f, 0.f};

    gemm_core256(A, Bt, D_, D_, D_, m0, n0, As, Bs, acc);

    const int wr = (wave >> 1) * 64;
    const int wc = (wave & 1) * 64;
    const int cr = (lane >> 4) * 4;
    const int cc = lane & 15;

#pragma unroll
    for (int mi = 0; mi < 4; mi++) {
#pragma unroll
        for (int ni = 0; ni < 4; ni++) {
            const int col = n0 + wc + ni * 16 + cc;
            const int seg = col >> 10;
            const int c = col & 1023;
            const float* bp = (seg == 0) ? bq : ((seg == 1) ? bk : bv);
            const float bval = bp[c];
#pragma unroll
            for (int r = 0; r < 4; r++) {
                const int row = m0 + wr + mi * 16 + cr + r;
                const unsigned short o = f2b(acc[mi][ni][r] + bval);
                if (seg == 0) {
                    Qb[(long long)row * D_ + c] = o;
                } else if (seg == 1) {
                    Kb[(long long)row * D_ + c] = o;
                } else {
                    const int b = row >> 11;
                    const int s = row & (S_ - 1);
                    Vt[((long long)b * D_ + c) * S_ + s] = o;
                }
            }
        }
    }
}

// ---------------------------------------------------------------------------
// AV reduce: bf16 out = p0 + p1 (bf16 partials)
// ---------------------------------------------------------------------------
__global__ __launch_bounds__(256) void avred_kernel(
    const ushort4* __restrict__ p0, const ushort4* __restrict__ p1,
    ushort4* __restrict__ dst, int n4)
{
    int i = blockIdx.x * 256 + threadIdx.x;
    if (i < n4) {
        ushort4 a = p0[i], b = p1[i];
        ushort4 u;
        u.x = f2b(b2f(a.x) + b2f(b.x)); u.y = f2b(b2f(a.y) + b2f(b.y));
        u.z = f2b(b2f(a.z) + b2f(b.z)); u.w = f2b(b2f(a.w) + b2f(b.w));
        dst[i] = u;
    }
}

// ---------------------------------------------------------------------------
// Fused split-K reduce + bias + residual + LayerNorm (fp32 partials).
// ---------------------------------------------------------------------------
template <int HAS_OUTB>
__global__ __launch_bounds__(256) void ln_red_kernel(
    const float* __restrict__ p0, const float* __restrict__ p1,
    const float* __restrict__ resid, const float* __restrict__ bias,
    const float* __restrict__ g, const float* __restrict__ b,
    float* __restrict__ out_f, unsigned short* __restrict__ out_b)
{
    __shared__ float red[8];
    const long long row = blockIdx.x;
    const int tid = threadIdx.x;
    const float4 a0 = ((const float4*)(p0 + row * D_))[tid];
    const float4 a1 = ((const float4*)(p1 + row * D_))[tid];
    const float4 rv = ((const float4*)(resid + row * D_))[tid];
    const float4 bi = ((const float4*)bias)[tid];
    float v0 = a0.x + a1.x + bi.x + rv.x;
    float v1 = a0.y + a1.y + bi.y + rv.y;
    float v2 = a0.z + a1.z + bi.z + rv.z;
    float v3 = a0.w + a1.w + bi.w + rv.w;

    float s = v0 + v1 + v2 + v3;
#pragma unroll
    for (int o = 32; o > 0; o >>= 1) s += __shfl_xor(s, o);
    if ((tid & 63) == 0) red[tid >> 6] = s;
    __syncthreads();
    const float mean = (red[0] + red[1] + red[2] + red[3]) * (1.0f / D_);

    const float d0 = v0 - mean, d1 = v1 - mean, d2 = v2 - mean, d3 = v3 - mean;
    float q = d0 * d0 + d1 * d1 + d2 * d2 + d3 * d3;
#pragma unroll
    for (int o = 32; o > 0; o >>= 1) q += __shfl_xor(q, o);
    if ((tid & 63) == 0) red[4 + (tid >> 6)] = q;
    __syncthreads();
    const float var = (red[4] + red[5] + red[6] + red[7]) * (1.0f / D_);
    const float inv = rsqrtf(var + 1e-6f);

    const float4 gv = ((const float4*)g)[tid];
    const float4 bv = ((const float4*)b)[tid];
    const float o0 = d0 * inv * gv.x + bv.x;
    const float o1 = d1 * inv * gv.y + bv.y;
    const float o2 = d2 * inv * gv.z + bv.z;
    const float o3 = d3 * inv * gv.w + bv.w;

    ((float4*)(out_f + row * D_))[tid] = float4{o0, o1, o2, o3};
    if (HAS_OUTB) {
        ushort4 u; u.x = f2b(o0); u.y = f2b(o1); u.z = f2b(o2); u.w = f2b(o3);
        ((ushort4*)(out_b + row * D_))[tid] = u;
    }
}

// ---------------------------------------------------------------------------
// softmax over rows of bf16 scores [B*S, S] + fp32 intensity -> bf16 attn
// ---------------------------------------------------------------------------
__global__ __launch_bounds__(256) void softmax_bias_kernel(
    const unsigned short* __restrict__ scores, const float* __restrict__ intensity,
    unsigned short* __restrict__ attn)
{
    __shared__ float red[8];
    const long long row = blockIdx.x;
    const int tid = threadIdx.x;
    const ushort4* s4 = (const ushort4*)(scores + row * S_);
    const float4* i4 = (const float4*)(intensity + row * S_);
    ushort4* dst = (ushort4*)(attn + row * S_);

    float vv[8];
    {
        ushort4 a = s4[tid], b = s4[tid + 256];
        vv[0] = b2f(a.x); vv[1] = b2f(a.y); vv[2] = b2f(a.z); vv[3] = b2f(a.w);
        vv[4] = b2f(b.x); vv[5] = b2f(b.y); vv[6] = b2f(b.z); vv[7] = b2f(b.w);
    }

    float mx = vv[0];
#pragma unroll
    for (int i = 1; i < 8; i++) mx = fmaxf(mx, vv[i]);
#pragma unroll
    for (int o = 32; o > 0; o >>= 1) mx = fmaxf(mx, __shfl_xor(mx, o));
    if ((tid & 63) == 0) red[tid >> 6] = mx;
    __syncthreads();
    mx = fmaxf(fmaxf(red[0], red[1]), fmaxf(red[2], red[3]));

    float e[8];
    float sum = 0.f;
#pragma unroll
    for (int i = 0; i < 8; i++) { e[i] = __expf(vv[i] - mx); sum += e[i]; }
#pragma unroll
    for (int o = 32; o > 0; o >>= 1) sum += __shfl_xor(sum, o);
    if ((tid & 63) == 0) red[4 + (tid >> 6)] = sum;
    __syncthreads();
    sum = red[4] + red[5] + red[6] + red[7];
    const float rs = 1.0f / sum;

#pragma unroll
    for (int i = 0; i < 2; i++) {
        float4 iv = i4[tid + 256 * i];
        ushort4 o;
        o.x = f2b(e[4 * i + 0] * rs + iv.x);
        o.y = f2b(e[4 * i + 1] * rs + iv.y);
        o.z = f2b(e[4 * i + 2] * rs + iv.z);
        o.w = f2b(e[4 * i + 3] * rs + iv.w);
        dst[tid + 256 * i] = o;
    }
}

// ---------------------------------------------------------------------------
extern "C" void kernel_launch(void* const* d_in, const int* in_sizes, int n_in,
                              void* d_out, int out_size, void* d_ws, size_t ws_size,
                              hipStream_t stream)
{
    const float* X   = (const float*)d_in[0];
    const float* inten = (const float*)d_in[1];
    const float* Wq  = (const float*)d_in[2];
    const float* bq  = (const float*)d_in[3];
    const float* Wk  = (const float*)d_in[4];
    const float* bk  = (const float*)d_in[5];
    const float* Wv  = (const float*)d_in[6];
    const float* bv  = (const float*)d_in[7];
    const float* Wo  = (const float*)d_in[8];
    const float* bo  = (const float*)d_in[9];
    const float* W1  = (const float*)d_in[10];
    const float* b1  = (const float*)d_in[11];
    const float* W2  = (const float*)d_in[12];
    const float* b2  = (const float*)d_in[13];
    const float* g1  = (const float*)d_in[14];
    const float* be1 = (const float*)d_in[15];
    const float* g2  = (const float*)d_in[16];
    const float* be2 = (const float*)d_in[17];
    float* out = (float*)d_out;

    char* ws = (char*)d_ws;
    const size_t MB = 1ull << 20;
    unsigned short* Xb   = (unsigned short*)(ws + 0);        // 16MB; dead after QKV
    unsigned short* Wqkv = (unsigned short*)(ws + 16 * MB);  // 6MB
    unsigned short* Wot  = (unsigned short*)(ws + 22 * MB);  // 2MB
    unsigned short* W1t  = (unsigned short*)(ws + 24 * MB);  // 8MB
    unsigned short* W2t  = (unsigned short*)(ws + 32 * MB);  // 8MB
    unsigned short* Qb   = (unsigned short*)(ws + 40 * MB);  // 16MB; dead after scores
    unsigned short* Kb   = (unsigned short*)(ws + 56 * MB);  // 16MB; dead after scores
    unsigned short* Vt   = (unsigned short*)(ws + 72 * MB);  // 16MB; dead after attnV
    unsigned short* Sc   = (unsigned short*)(ws + 88 * MB);  // 32MB bf16; dead after softmax
    unsigned short* At   = (unsigned short*)(ws + 152 * MB); // 32MB; dead after attnV
    unsigned short* AVp  = (unsigned short*)(ws + 88 * MB);  // 32MB bf16 (2 parts; reuse Sc)
    unsigned short* AVb  = (unsigned short*)(ws + 0);        // 16MB (reuse Xb)
    float*          Op   = (float*)(ws + 152 * MB);          // 64MB fp32 (2 parts; reuse At)
    float*          Hf   = (float*)(ws + 40 * MB);           // 32MB (reuse Qb+Kb)
    unsigned short* Hb   = (unsigned short*)(ws + 72 * MB);  // 16MB (reuse Vt)
    unsigned short* F1   = (unsigned short*)(ws + 88 * MB);  // 64MB (reuse AVp+)
    float*          Fp   = (float*)(ws + 152 * MB);          // 64MB fp32 (2 parts; reuse Op)

    const dim3 blk(256);
    const dim3 blk512(512);
    const dim3 tblk(32, 8);
    const long long MN_d = (long long)B_ * S_ * D_;

    // casts / weight transposes
    cast_bf16_kernel<<<dim3(8192), blk, 0, stream>>>(
        (const float4*)X, (ushort4*)Xb, B_ * S_ * D_ / 4);
    transpose_cast_kernel<<<dim3(D_ / 32, D_ / 32), tblk, 0, stream>>>(
        Wq, Wqkv, D_, D_);
    transpose_cast_kernel<<<dim3(D_ / 32, D_ / 32), tblk, 0, stream>>>(
        Wk, Wqkv + 1024 * 1024, D_, D_);
    transpose_cast_kernel<<<dim3(D_ / 32, D_ / 32), tblk, 0, stream>>>(
        Wv, Wqkv + 2048 * 1024, D_, D_);
    transpose_cast_kernel<<<dim3(D_ / 32, D_ / 32), tblk, 0, stream>>>(Wo, Wot, D_, D_);
    transpose_cast_kernel<<<dim3(DFF_ / 32, D_ / 32), tblk, 0, stream>>>(W1, W1t, D_, DFF_);
    transpose_cast_kernel<<<dim3(D_ / 32, DFF_ / 32), tblk, 0, stream>>>(W2, W2t, DFF_, D_);

    // fused QKV: 768 blocks x 8 waves
    gemm_qkv<<<dim3(24, 32), blk512, 0, stream>>>(Xb, Wqkv, Qb, Kb, Vt, bq, bk, bv);

    // scores = Q @ K^T / 32 -> bf16, 512 blocks
    gemm_bt<1, 0, 0><<<dim3(16, 8, 4), blk512, 0, stream>>>(
        Qb, Kb, Sc, nullptr, S_, S_, D_, 0.03125f,
        (long long)S_ * D_, (long long)S_ * D_, (long long)S_ * S_);

    // attn = softmax(scores) + intensity  (bf16)
    softmax_bias_kernel<<<dim3(B_ * S_), blk, 0, stream>>>(Sc, inten, At);

    // AV split-K=2: bf16 partials, 512 blocks
    gemm_bt_sk<2, 1><<<dim3(8, 8, 8), blk512, 0, stream>>>(
        At, Vt, AVp, S_, D_, S_ / 2, S_, S_,
        (long long)S_ * S_, (long long)D_ * S_);
    avred_kernel<<<dim3(8192), blk, 0, stream>>>(
        (const ushort4*)AVp, (const ushort4*)(AVp + MN_d), (ushort4*)AVb,
        (int)(MN_d / 4));

    // O-proj split-K=2: fp32 partials, 512 blocks
    gemm_bt_sk<2, 0><<<dim3(8, 32, 2), blk512, 0, stream>>>(
        AVb, Wot, Op, B_ * S_, D_, D_ / 2, D_, D_, 0, 0);

    // h = LN(Op0 + Op1 + bo + X) -> Hf fp32 + Hb bf16
    ln_red_kernel<1><<<dim3(B_ * S_), blk, 0, stream>>>(
        Op, Op + MN_d, X, bo, g1, be1, Hf, Hb);

    // F1 = leaky_relu(h @ W1 + b1)  (bf16), 1024 blocks
    gemm_bt<1, 1, 1><<<dim3(32, 32), blk512, 0, stream>>>(
        Hb, W1t, F1, b1, B_ * S_, DFF_, D_, 1.0f, 0, 0, 0);

    // ffn2 split-K=2: fp32 partials, 512 blocks
    gemm_bt_sk<2, 0><<<dim3(8, 32, 2), blk512, 0, stream>>>(
        F1, W2t, Fp, B_ * S_, D_, DFF_ / 2, DFF_, DFF_, 0, 0);

    // out = LN(Fp0 + Fp1 + b2 + h)
    ln_red_kernel<0><<<dim3(B_ * S_), blk, 0, stream>>>(
        Fp, Fp + MN_d, Hf, b2, g2, be2, out, nullptr);
}

// Round 7
// 560.067 us; speedup vs baseline: 1.2695x; 1.0289x over previous
//
#include <hip/hip_runtime.h>

#define B_   4
#define S_   2048
#define D_   1024
#define DFF_ 4096

typedef __attribute__((ext_vector_type(8))) short short8;
typedef __attribute__((ext_vector_type(4))) float floatx4;

__device__ __forceinline__ unsigned short f2b(float f) {
    unsigned int u = __float_as_uint(f);
    unsigned int r = (u + 0x7fffu + ((u >> 16) & 1u)) >> 16;
    return (unsigned short)r;
}
__device__ __forceinline__ float b2f(unsigned short u) {
    return __uint_as_float((unsigned int)u << 16);
}

// XCD-aware swizzle: blocks sharing an A row-tile (same by) land on one XCD.
__device__ __forceinline__ void swizzle_xy(int gx, int gy, int& bx, int& by) {
    if ((gy & 7) == 0) {
        const int linear = by * gx + bx;
        const int xcd = linear & 7;
        const int slot = linear >> 3;
        const int r = slot / gx;
        by = xcd * (gy >> 3) + r;
        bx = slot - r * gx;
    }
}

// ---------------------------------------------------------------------------
// GEMM core: 256x128 tile, BK=64, 512 threads / 8 waves (each 64x64).
// 2-barrier K-loop. XOR swizzle g ^ (r&7) -> conflict-free b128 frag reads.
// ---------------------------------------------------------------------------
__device__ __forceinline__ void gemm_core256(
    const unsigned short* __restrict__ A,
    const unsigned short* __restrict__ Bt,
    int ldA, int ldB, int K, int m0, int n0,
    unsigned short* As, unsigned short* Bs,
    floatx4 acc[4][4])
{
    const int tid  = threadIdx.x;   // 0..511
    const int lane = tid & 63;
    const int wave = tid >> 6;      // 0..7

    const int ra = tid >> 3;        // 0..63 (row within pass)
    const int pg = tid & 7;         // physical k-group
    const int cg = (pg ^ (ra & 7)) * 8;   // logical k-group loaded
    const unsigned short* gA = A  + (long long)(m0 + ra) * ldA + cg;
    const unsigned short* gB = Bt + (long long)(n0 + ra) * ldB + cg;
    const long long pA = 64LL * ldA;
    const long long pB = 64LL * ldB;

    unsigned short* dA = As + wave * 512;
    unsigned short* dB = Bs + wave * 512;

    const int wr = (wave >> 1) * 64;  // 0..192
    const int wc = (wave & 1) * 64;   // 0 or 64
    const int fr = lane & 15;
    const int q  = lane >> 4;

    int aoff[2][4], boff[2][4];
#pragma unroll
    for (int h = 0; h < 2; h++)
#pragma unroll
        for (int i = 0; i < 4; i++) {
            const int rA = wr + i * 16 + fr;
            const int rB = wc + i * 16 + fr;
            const int g  = h * 4 + q;
            aoff[h][i] = rA * 64 + ((g ^ (rA & 7)) * 8);
            boff[h][i] = rB * 64 + ((g ^ (rB & 7)) * 8);
        }

    for (int k0 = 0; k0 < K; k0 += 64) {
        __syncthreads();
#pragma unroll
        for (int p = 0; p < 4; p++)
            __builtin_amdgcn_global_load_lds(
                (const __attribute__((address_space(1))) void*)(gA + k0 + p * pA),
                (__attribute__((address_space(3))) void*)(dA + p * 4096), 16, 0, 0);
#pragma unroll
        for (int p = 0; p < 2; p++)
            __builtin_amdgcn_global_load_lds(
                (const __attribute__((address_space(1))) void*)(gB + k0 + p * pB),
                (__attribute__((address_space(3))) void*)(dB + p * 4096), 16, 0, 0);
        __syncthreads();

#pragma unroll
        for (int h = 0; h < 2; h++) {
            short8 af[4], bfr[4];
#pragma unroll
            for (int mi = 0; mi < 4; mi++) af[mi] = *(const short8*)&As[aoff[h][mi]];
#pragma unroll
            for (int ni = 0; ni < 4; ni++) bfr[ni] = *(const short8*)&Bs[boff[h][ni]];
#pragma unroll
            for (int mi = 0; mi < 4; mi++)
#pragma unroll
                for (int ni = 0; ni < 4; ni++)
                    acc[mi][ni] = __builtin_amdgcn_mfma_f32_16x16x32_bf16(
                        af[mi], bfr[ni], acc[mi][ni], 0, 0, 0);
        }
    }
}

// ---------------------------------------------------------------------------
__global__ __launch_bounds__(256) void cast_bf16_kernel(
    const float4* __restrict__ src, ushort4* __restrict__ dst, int n4)
{
    int i = blockIdx.x * 256 + threadIdx.x;
    if (i < n4) {
        float4 f = src[i];
        ushort4 u;
        u.x = f2b(f.x); u.y = f2b(f.y); u.z = f2b(f.z); u.w = f2b(f.w);
        dst[i] = u;
    }
}

// ---------------------------------------------------------------------------
__global__ __launch_bounds__(256) void transpose_cast_kernel(
    const float* __restrict__ W, unsigned short* __restrict__ Wt, int K, int N)
{
    __shared__ float tile[32][33];
    const int tx = threadIdx.x;
    const int ty = threadIdx.y;
    const int bx = blockIdx.x * 32;
    const int by = blockIdx.y * 32;
#pragma unroll
    for (int j = 0; j < 32; j += 8)
        tile[ty + j][tx] = W[(long long)(by + ty + j) * N + bx + tx];
    __syncthreads();
#pragma unroll
    for (int j = 0; j < 32; j += 8)
        Wt[(long long)(bx + ty + j) * K + by + tx] = f2b(tile[tx][ty + j]);
}

// ---------------------------------------------------------------------------
// bf16 transpose: Vb [B][S][D] -> Vt [B][D][S]. 64x64 LDS tiles, ushort4 IO.
// ---------------------------------------------------------------------------
__global__ __launch_bounds__(256) void vtrans_kernel(
    const unsigned short* __restrict__ Vb, unsigned short* __restrict__ Vt)
{
    __shared__ unsigned short tile[64][68];
    const int b  = blockIdx.z;
    const int s0 = blockIdx.y * 64;
    const int d0 = blockIdx.x * 64;
    const int tx = threadIdx.x & 15;
    const int ty = threadIdx.x >> 4;

    const unsigned short* src = Vb + ((long long)b * S_ + s0) * D_ + d0;
#pragma unroll
    for (int j = 0; j < 4; j++) {
        const int s = j * 16 + ty;
        ushort4 v = *(const ushort4*)(src + (long long)s * D_ + tx * 4);
        tile[tx * 4 + 0][s] = v.x;
        tile[tx * 4 + 1][s] = v.y;
        tile[tx * 4 + 2][s] = v.z;
        tile[tx * 4 + 3][s] = v.w;
    }
    __syncthreads();
    unsigned short* dst = Vt + ((long long)b * D_ + d0) * S_ + s0;
#pragma unroll
    for (int j = 0; j < 4; j++) {
        const int d = j * 16 + ty;
        ushort4 v;
        v.x = tile[d][tx * 4 + 0];
        v.y = tile[d][tx * 4 + 1];
        v.z = tile[d][tx * 4 + 2];
        v.w = tile[d][tx * 4 + 3];
        *(ushort4*)(dst + (long long)d * S_ + tx * 4) = v;
    }
}

// ---------------------------------------------------------------------------
// GEMM: C = act(scale * A @ Bt^T + bias), batched via z. 256x128 tile.
// ---------------------------------------------------------------------------
template <int OUT_BF16, int ACT_LEAKY, int HAS_BIAS>
__global__ __launch_bounds__(512, 4) void gemm_bt(
    const unsigned short* __restrict__ A,
    const unsigned short* __restrict__ Bt,
    void* __restrict__ Cptr,
    const float* __restrict__ bias,
    int M, int N, int K, float scale,
    long long sA, long long sB, long long sC)
{
    __shared__ unsigned short As[256 * 64];
    __shared__ unsigned short Bs[128 * 64];

    const int lane = threadIdx.x & 63;
    const int wave = threadIdx.x >> 6;
    const int z    = blockIdx.z;

    int bx = blockIdx.x, by = blockIdx.y;
    swizzle_xy(gridDim.x, gridDim.y, bx, by);
    const int m0 = by * 256;
    const int n0 = bx * 128;

    floatx4 acc[4][4];
#pragma unroll
    for (int i = 0; i < 4; i++)
#pragma unroll
        for (int j = 0; j < 4; j++) acc[i][j] = floatx4{0.f, 0.f, 0.f, 0.f};

    gemm_core256(A + (long long)z * sA, Bt + (long long)z * sB,
                 K, K, K, m0, n0, As, Bs, acc);

    const int wr = (wave >> 1) * 64;
    const int wc = (wave & 1) * 64;
    const int cr = (lane >> 4) * 4;
    const int cc = lane & 15;
    float* Cf = (float*)Cptr;
    unsigned short* Cb = (unsigned short*)Cptr;

#pragma unroll
    for (int mi = 0; mi < 4; mi++) {
#pragma unroll
        for (int ni = 0; ni < 4; ni++) {
            const int col = n0 + wc + ni * 16 + cc;
            const float bv = HAS_BIAS ? bias[col] : 0.0f;
#pragma unroll
            for (int r = 0; r < 4; r++) {
                const int row = m0 + wr + mi * 16 + cr + r;
                float v = acc[mi][ni][r] * scale + bv;
                if (ACT_LEAKY) v = (v > 0.0f) ? v : 0.01f * v;
                const long long idx = (long long)z * sC + (long long)row * N + col;
                if (OUT_BF16) Cb[idx] = f2b(v); else Cf[idx] = v;
            }
        }
    }
}

// ---------------------------------------------------------------------------
// Split-K GEMM, 256x128 tile: blockIdx.z = b * NK + ks;
// partial P[(ks*nb + b)][M][N] stored bf16.
// ---------------------------------------------------------------------------
template <int NK>
__global__ __launch_bounds__(512, 4) void gemm_bt_sk(
    const unsigned short* __restrict__ A,
    const unsigned short* __restrict__ Bt,
    unsigned short* __restrict__ P,
    int M, int N, int Kslice, int ldA, int ldB,
    long long sA, long long sB)
{
    __shared__ unsigned short As[256 * 64];
    __shared__ unsigned short Bs[128 * 64];

    const int lane = threadIdx.x & 63;
    const int wave = threadIdx.x >> 6;
    const int z    = blockIdx.z;
    const int ks   = z % NK;
    const int b    = z / NK;
    const int nb   = gridDim.z / NK;

    int bx = blockIdx.x, by = blockIdx.y;
    swizzle_xy(gridDim.x, gridDim.y, bx, by);
    const int m0 = by * 256;
    const int n0 = bx * 128;

    floatx4 acc[4][4];
#pragma unroll
    for (int i = 0; i < 4; i++)
#pragma unroll
        for (int j = 0; j < 4; j++) acc[i][j] = floatx4{0.f, 0.f, 0.f, 0.f};

    gemm_core256(A + (long long)b * sA + (long long)ks * Kslice,
                 Bt + (long long)b * sB + (long long)ks * Kslice,
                 ldA, ldB, Kslice, m0, n0, As, Bs, acc);

    const long long pbase = ((long long)ks * nb + b) * (long long)M * N;

    const int wr = (wave >> 1) * 64;
    const int wc = (wave & 1) * 64;
    const int cr = (lane >> 4) * 4;
    const int cc = lane & 15;

#pragma unroll
    for (int mi = 0; mi < 4; mi++) {
#pragma unroll
        for (int ni = 0; ni < 4; ni++) {
            const int col = n0 + wc + ni * 16 + cc;
#pragma unroll
            for (int r = 0; r < 4; r++) {
                const int row = m0 + wr + mi * 16 + cr + r;
                P[pbase + (long long)row * N + col] = f2b(acc[mi][ni][r]);
            }
        }
    }
}

// ---------------------------------------------------------------------------
// Fused QKV GEMM, 256x128 tile: A[8192,1024] @ Wqkvt[3072,1024]^T
// All three segments write coalesced [row][c]; V transposed separately.
// ---------------------------------------------------------------------------
__global__ __launch_bounds__(512, 4) void gemm_qkv(
    const unsigned short* __restrict__ A,
    const unsigned short* __restrict__ Bt,
    unsigned short* __restrict__ Qb,
    unsigned short* __restrict__ Kb,
    unsigned short* __restrict__ Vb,
    const float* __restrict__ bq,
    const float* __restrict__ bk,
    const float* __restrict__ bv)
{
    __shared__ unsigned short As[256 * 64];
    __shared__ unsigned short Bs[128 * 64];

    const int lane = threadIdx.x & 63;
    const int wave = threadIdx.x >> 6;

    int bx = blockIdx.x, by = blockIdx.y;
    swizzle_xy(gridDim.x, gridDim.y, bx, by);
    const int m0 = by * 256;
    const int n0 = bx * 128;

    floatx4 acc[4][4];
#pragma unroll
    for (int i = 0; i < 4; i++)
#pragma unroll
        for (int j = 0; j < 4; j++) acc[i][j] = floatx4{0.f, 0.f, 0.f, 0.f};

    gemm_core256(A, Bt, D_, D_, D_, m0, n0, As, Bs, acc);

    const int wr = (wave >> 1) * 64;
    const int wc = (wave & 1) * 64;
    const int cr = (lane >> 4) * 4;
    const int cc = lane & 15;

#pragma unroll
    for (int mi = 0; mi < 4; mi++) {
#pragma unroll
        for (int ni = 0; ni < 4; ni++) {
            const int col = n0 + wc + ni * 16 + cc;
            const int seg = col >> 10;
            const int c = col & 1023;
            const float* bp = (seg == 0) ? bq : ((seg == 1) ? bk : bv);
            unsigned short* dp = (seg == 0) ? Qb : ((seg == 1) ? Kb : Vb);
            const float bval = bp[c];
#pragma unroll
            for (int r = 0; r < 4; r++) {
                const int row = m0 + wr + mi * 16 + cr + r;
                dp[(long long)row * D_ + c] = f2b(acc[mi][ni][r] + bval);
            }
        }
    }
}

// ---------------------------------------------------------------------------
// AV reduce: bf16 out = p0 + p1 (bf16 partials)
// ---------------------------------------------------------------------------
__global__ __launch_bounds__(256) void avred_kernel(
    const ushort4* __restrict__ p0, const ushort4* __restrict__ p1,
    ushort4* __restrict__ dst, int n4)
{
    int i = blockIdx.x * 256 + threadIdx.x;
    if (i < n4) {
        ushort4 a = p0[i], b = p1[i];
        ushort4 u;
        u.x = f2b(b2f(a.x) + b2f(b.x)); u.y = f2b(b2f(a.y) + b2f(b.y));
        u.z = f2b(b2f(a.z) + b2f(b.z)); u.w = f2b(b2f(a.w) + b2f(b.w));
        dst[i] = u;
    }
}

// ---------------------------------------------------------------------------
// Fused split-K reduce + bias + residual + LayerNorm (bf16 partials).
// ---------------------------------------------------------------------------
template <int HAS_OUTB>
__global__ __launch_bounds__(256) void ln_red_kernel(
    const unsigned short* __restrict__ p0, const unsigned short* __restrict__ p1,
    const float* __restrict__ resid, const float* __restrict__ bias,
    const float* __restrict__ g, const float* __restrict__ b,
    float* __restrict__ out_f, unsigned short* __restrict__ out_b)
{
    __shared__ float red[8];
    const long long row = blockIdx.x;
    const int tid = threadIdx.x;
    const ushort4 a0 = ((const ushort4*)(p0 + row * D_))[tid];
    const ushort4 a1 = ((const ushort4*)(p1 + row * D_))[tid];
    const float4 rv = ((const float4*)(resid + row * D_))[tid];
    const float4 bi = ((const float4*)bias)[tid];
    float v0 = b2f(a0.x) + b2f(a1.x) + bi.x + rv.x;
    float v1 = b2f(a0.y) + b2f(a1.y) + bi.y + rv.y;
    float v2 = b2f(a0.z) + b2f(a1.z) + bi.z + rv.z;
    float v3 = b2f(a0.w) + b2f(a1.w) + bi.w + rv.w;

    float s = v0 + v1 + v2 + v3;
#pragma unroll
    for (int o = 32; o > 0; o >>= 1) s += __shfl_xor(s, o);
    if ((tid & 63) == 0) red[tid >> 6] = s;
    __syncthreads();
    const float mean = (red[0] + red[1] + red[2] + red[3]) * (1.0f / D_);

    const float d0 = v0 - mean, d1 = v1 - mean, d2 = v2 - mean, d3 = v3 - mean;
    float q = d0 * d0 + d1 * d1 + d2 * d2 + d3 * d3;
#pragma unroll
    for (int o = 32; o > 0; o >>= 1) q += __shfl_xor(q, o);
    if ((tid & 63) == 0) red[4 + (tid >> 6)] = q;
    __syncthreads();
    const float var = (red[4] + red[5] + red[6] + red[7]) * (1.0f / D_);
    const float inv = rsqrtf(var + 1e-6f);

    const float4 gv = ((const float4*)g)[tid];
    const float4 bv = ((const float4*)b)[tid];
    const float o0 = d0 * inv * gv.x + bv.x;
    const float o1 = d1 * inv * gv.y + bv.y;
    const float o2 = d2 * inv * gv.z + bv.z;
    const float o3 = d3 * inv * gv.w + bv.w;

    ((float4*)(out_f + row * D_))[tid] = float4{o0, o1, o2, o3};
    if (HAS_OUTB) {
        ushort4 u; u.x = f2b(o0); u.y = f2b(o1); u.z = f2b(o2); u.w = f2b(o3);
        ((ushort4*)(out_b + row * D_))[tid] = u;
    }
}

// ---------------------------------------------------------------------------
// softmax over rows of bf16 scores [B*S, S] + fp32 intensity -> bf16 attn
// ---------------------------------------------------------------------------
__global__ __launch_bounds__(256) void softmax_bias_kernel(
    const unsigned short* __restrict__ scores, const float* __restrict__ intensity,
    unsigned short* __restrict__ attn)
{
    __shared__ float red[8];
    const long long row = blockIdx.x;
    const int tid = threadIdx.x;
    const ushort4* s4 = (const ushort4*)(scores + row * S_);
    const float4* i4 = (const float4*)(intensity + row * S_);
    ushort4* dst = (ushort4*)(attn + row * S_);

    float vv[8];
    {
        ushort4 a = s4[tid], b = s4[tid + 256];
        vv[0] = b2f(a.x); vv[1] = b2f(a.y); vv[2] = b2f(a.z); vv[3] = b2f(a.w);
        vv[4] = b2f(b.x); vv[5] = b2f(b.y); vv[6] = b2f(b.z); vv[7] = b2f(b.w);
    }

    float mx = vv[0];
#pragma unroll
    for (int i = 1; i < 8; i++) mx = fmaxf(mx, vv[i]);
#pragma unroll
    for (int o = 32; o > 0; o >>= 1) mx = fmaxf(mx, __shfl_xor(mx, o));
    if ((tid & 63) == 0) red[tid >> 6] = mx;
    __syncthreads();
    mx = fmaxf(fmaxf(red[0], red[1]), fmaxf(red[2], red[3]));

    float e[8];
    float sum = 0.f;
#pragma unroll
    for (int i = 0; i < 8; i++) { e[i] = __expf(vv[i] - mx); sum += e[i]; }
#pragma unroll
    for (int o = 32; o > 0; o >>= 1) sum += __shfl_xor(sum, o);
    if ((tid & 63) == 0) red[4 + (tid >> 6)] = sum;
    __syncthreads();
    sum = red[4] + red[5] + red[6] + red[7];
    const float rs = 1.0f / sum;

#pragma unroll
    for (int i = 0; i < 2; i++) {
        float4 iv = i4[tid + 256 * i];
        ushort4 o;
        o.x = f2b(e[4 * i + 0] * rs + iv.x);
        o.y = f2b(e[4 * i + 1] * rs + iv.y);
        o.z = f2b(e[4 * i + 2] * rs + iv.z);
        o.w = f2b(e[4 * i + 3] * rs + iv.w);
        dst[tid + 256 * i] = o;
    }
}

// ---------------------------------------------------------------------------
extern "C" void kernel_launch(void* const* d_in, const int* in_sizes, int n_in,
                              void* d_out, int out_size, void* d_ws, size_t ws_size,
                              hipStream_t stream)
{
    const float* X   = (const float*)d_in[0];
    const float* inten = (const float*)d_in[1];
    const float* Wq  = (const float*)d_in[2];
    const float* bq  = (const float*)d_in[3];
    const float* Wk  = (const float*)d_in[4];
    const float* bk  = (const float*)d_in[5];
    const float* Wv  = (const float*)d_in[6];
    const float* bv  = (const float*)d_in[7];
    const float* Wo  = (const float*)d_in[8];
    const float* bo  = (const float*)d_in[9];
    const float* W1  = (const float*)d_in[10];
    const float* b1  = (const float*)d_in[11];
    const float* W2  = (const float*)d_in[12];
    const float* b2  = (const float*)d_in[13];
    const float* g1  = (const float*)d_in[14];
    const float* be1 = (const float*)d_in[15];
    const float* g2  = (const float*)d_in[16];
    const float* be2 = (const float*)d_in[17];
    float* out = (float*)d_out;

    char* ws = (char*)d_ws;
    const size_t MB = 1ull << 20;
    // timeline-aliased layout, peak 184 MB:
    unsigned short* Xb   = (unsigned short*)(ws + 0);        // 16MB; dead after QKV
    unsigned short* Wqkv = (unsigned short*)(ws + 16 * MB);  // 6MB
    unsigned short* Wot  = (unsigned short*)(ws + 22 * MB);  // 2MB
    unsigned short* W1t  = (unsigned short*)(ws + 24 * MB);  // 8MB
    unsigned short* W2t  = (unsigned short*)(ws + 32 * MB);  // 8MB
    unsigned short* Qb   = (unsigned short*)(ws + 40 * MB);  // 16MB; dead after scores
    unsigned short* Kb   = (unsigned short*)(ws + 56 * MB);  // 16MB; dead after scores
    unsigned short* Vt   = (unsigned short*)(ws + 72 * MB);  // 16MB; dead after attnV
    unsigned short* Sc   = (unsigned short*)(ws + 88 * MB);  // 32MB bf16; dead after softmax
    unsigned short* Vb   = (unsigned short*)(ws + 152 * MB); // 16MB; dead after vtrans
    unsigned short* At   = (unsigned short*)(ws + 152 * MB); // 32MB (after Vb dead); dead after AV
    unsigned short* AVp  = (unsigned short*)(ws + 88 * MB);  // 2x16MB bf16 (reuse Sc)
    unsigned short* AVb  = (unsigned short*)(ws + 0);        // 16MB (reuse Xb)
    unsigned short* Op   = (unsigned short*)(ws + 152 * MB); // 2x16MB bf16 (reuse At)
    float*          Hf   = (float*)(ws + 40 * MB);           // 32MB (reuse Qb+Kb)
    unsigned short* Hb   = (unsigned short*)(ws + 72 * MB);  // 16MB (reuse Vt)
    unsigned short* F1   = (unsigned short*)(ws + 88 * MB);  // 64MB (reuse AVp + free)
    unsigned short* Fp   = (unsigned short*)(ws + 152 * MB); // 2x16MB bf16 (reuse Op)

    const dim3 blk(256);
    const dim3 blk512(512);
    const dim3 tblk(32, 8);
    const long long MN_d = (long long)B_ * S_ * D_;

    // casts / weight transposes
    cast_bf16_kernel<<<dim3(8192), blk, 0, stream>>>(
        (const float4*)X, (ushort4*)Xb, B_ * S_ * D_ / 4);
    transpose_cast_kernel<<<dim3(D_ / 32, D_ / 32), tblk, 0, stream>>>(
        Wq, Wqkv, D_, D_);
    transpose_cast_kernel<<<dim3(D_ / 32, D_ / 32), tblk, 0, stream>>>(
        Wk, Wqkv + 1024 * 1024, D_, D_);
    transpose_cast_kernel<<<dim3(D_ / 32, D_ / 32), tblk, 0, stream>>>(
        Wv, Wqkv + 2048 * 1024, D_, D_);
    transpose_cast_kernel<<<dim3(D_ / 32, D_ / 32), tblk, 0, stream>>>(Wo, Wot, D_, D_);
    transpose_cast_kernel<<<dim3(DFF_ / 32, D_ / 32), tblk, 0, stream>>>(W1, W1t, D_, DFF_);
    transpose_cast_kernel<<<dim3(D_ / 32, DFF_ / 32), tblk, 0, stream>>>(W2, W2t, DFF_, D_);

    // fused QKV: 768 blocks x 8 waves; all outputs coalesced
    gemm_qkv<<<dim3(24, 32), blk512, 0, stream>>>(Xb, Wqkv, Qb, Kb, Vb, bq, bk, bv);

    // Vt[b][d][s] = transpose(Vb[b][s][d])
    vtrans_kernel<<<dim3(D_ / 64, S_ / 64, B_), blk, 0, stream>>>(Vb, Vt);

    // scores = Q @ K^T / 32 -> bf16, 512 blocks
    gemm_bt<1, 0, 0><<<dim3(16, 8, 4), blk512, 0, stream>>>(
        Qb, Kb, Sc, nullptr, S_, S_, D_, 0.03125f,
        (long long)S_ * D_, (long long)S_ * D_, (long long)S_ * S_);

    // attn = softmax(scores) + intensity  (bf16)
    softmax_bias_kernel<<<dim3(B_ * S_), blk, 0, stream>>>(Sc, inten, At);

    // AV split-K=2: bf16 partials, 512 blocks
    gemm_bt_sk<2><<<dim3(8, 8, 8), blk512, 0, stream>>>(
        At, Vt, AVp, S_, D_, S_ / 2, S_, S_,
        (long long)S_ * S_, (long long)D_ * S_);
    avred_kernel<<<dim3(8192), blk, 0, stream>>>(
        (const ushort4*)AVp, (const ushort4*)(AVp + MN_d), (ushort4*)AVb,
        (int)(MN_d / 4));

    // O-proj split-K=2: bf16 partials, 512 blocks
    gemm_bt_sk<2><<<dim3(8, 32, 2), blk512, 0, stream>>>(
        AVb, Wot, Op, B_ * S_, D_, D_ / 2, D_, D_, 0, 0);

    // h = LN(Op0 + Op1 + bo + X) -> Hf fp32 + Hb bf16
    ln_red_kernel<1><<<dim3(B_ * S_), blk, 0, stream>>>(
        Op, Op + MN_d, X, bo, g1, be1, Hf, Hb);

    // F1 = leaky_relu(h @ W1 + b1)  (bf16), 1024 blocks
    gemm_bt<1, 1, 1><<<dim3(32, 32), blk512, 0, stream>>>(
        Hb, W1t, F1, b1, B_ * S_, DFF_, D_, 1.0f, 0, 0, 0);

    // ffn2 split-K=2: bf16 partials, 512 blocks
    gemm_bt_sk<2><<<dim3(8, 32, 2), blk512, 0, stream>>>(
        F1, W2t, Fp, B_ * S_, D_, DFF_ / 2, DFF_, DFF_, 0, 0);

    // out = LN(Fp0 + Fp1 + b2 + h)
    ln_red_kernel<0><<<dim3(B_ * S_), blk, 0, stream>>>(
        Fp, Fp + MN_d, Hf, b2, g2, be2, out, nullptr);
}